// Round 2
// baseline (677.612 us; speedup 1.0000x reference)
//
#include <hip/hip_runtime.h>

// Problem constants (from reference)
#define Bsz 16
#define Cc  256
#define Ll  4096
#define Pp  100
#define Qq  20
#define LT  64            // l-tile per block (= one wave of lanes)
#define NLB (Ll / LT)     // 64 l-blocks
#define PPW 25            // p's handled per wave (4 waves x 25 = P=100)
#define PQ  (Pp * Qq)     // 2000

// ---------------------------------------------------------------------------
// Main fused kernel.
// NUMERICS CONTRACT (matches numpy fp32 reference bit-for-bit):
//   a[b,p,l] = chain over c=0..255 of  a = fmaf(X[b,c,l], proj[p,c], a)   [fp32]
//   thr[p,q] = fadd(mn, fmul(fsub(mx,mn), fdiv(q+1, 21)))                 [fp32,
//              separate roundings, NO contraction]
//   set = (a < thr) ? 1.0f : 0.0f ;  cdf = popcount/4096 (exact)
// Grid: (NLB, Bsz). Block: 256 = 4 waves; wave w owns p in [25w, 25w+25);
// lane = l within the 64-wide l-tile.
// ---------------------------------------------------------------------------
__global__ __launch_bounds__(256) void csf_main(
    const float* __restrict__ X,
    const float* __restrict__ proj,
    const float* __restrict__ mn,
    const float* __restrict__ mx,
    float* __restrict__ cdf,       // d_out[0 .. B*P*Q)
    float* __restrict__ set_out,   // d_out + B*P*Q
    float* __restrict__ counts,    // ws per-block counts (or nullptr)
    int use_atomic) {
    const int lblk = blockIdx.x;                // 0..63
    const int b    = blockIdx.y;                // 0..15
    const int tid  = threadIdx.x;
    const int lane = tid & 63;
    // wave-uniform p-group so proj/mn/mx indexing scalarizes to s_load
    const int pg   = __builtin_amdgcn_readfirstlane(tid >> 6);  // 0..3
    const int l    = lblk * LT + lane;

    const float* Xb = X + (size_t)b * Cc * Ll + l;   // element c at Xb[c*Ll]
    const int p0 = pg * PPW;
    const float* pj = proj + (size_t)p0 * Cc;        // pj[i*Cc + c]

    float acc[PPW];
#pragma unroll
    for (int i = 0; i < PPW; i++) acc[i] = 0.0f;

    // Sequential-in-c fp32 FMA chain (exact replication of np.einsum order).
    // c unrolled by 8 for load ILP; per-acc chain order is preserved.
    for (int c = 0; c < Cc; c += 8) {
        float x[8];
#pragma unroll
        for (int u = 0; u < 8; u++) x[u] = Xb[(size_t)(c + u) * Ll];
#pragma unroll
        for (int i = 0; i < PPW; i++) {
            const float* pr = pj + i * Cc + c;
            float a = acc[i];
#pragma unroll
            for (int u = 0; u < 8; u++) a = __builtin_fmaf(x[u], pr[u], a);
            acc[i] = a;
        }
    }

    // fracs: fl((q+1)/21) — IEEE-correct division, same as np.arange/np.float32(21)
    float fr[Qq];
#pragma unroll
    for (int q = 0; q < Qq; q++) fr[q] = __fdiv_rn((float)(q + 1), 21.0f);

    // Epilogue: compare vs 20 thresholds, write set bits + per-block counts.
    float* ob = set_out + (size_t)b * PQ * Ll + l;    // + (p*Q+q)*Ll
#pragma unroll 1
    for (int i = 0; i < PPW; i++) {
        const int p = p0 + i;
        const float a = acc[i];
        const float mnp = mn[p];
        const float mxp = mx[p];
        const float d = __fsub_rn(mxp, mnp);          // fl(mx-mn)
#pragma unroll
        for (int q = 0; q < Qq; q++) {
            // fl(mn + fl(d*frac)) — separate roundings, no FMA contraction
            const float thr = __fadd_rn(mnp, __fmul_rn(d, fr[q]));
            const bool bit = a < thr;
            const unsigned long long m = __ballot(bit);
            ob[(size_t)(p * Qq + q) * Ll] = bit ? 1.0f : 0.0f;
            if (lane == 0) {
                const float cnt = (float)__popcll(m);
                if (use_atomic) {
                    atomicAdd(&cdf[(size_t)b * PQ + p * Qq + q],
                              cnt * (1.0f / (float)Ll));  // exact: multiples of 2^-12
                } else {
                    counts[((size_t)(b * NLB + lblk)) * PQ + p * Qq + q] = cnt;
                }
            }
        }
    }
}

// ---------------------------------------------------------------------------
// Reduce per-block counts -> cdf. Exact integer sums, /4096 exact in fp32.
// ---------------------------------------------------------------------------
__global__ void csf_reduce(const float* __restrict__ counts,
                           float* __restrict__ cdf) {
    int idx = blockIdx.x * blockDim.x + threadIdx.x;
    if (idx >= Bsz * PQ) return;
    int b = idx / PQ;
    int r = idx % PQ;
    float s = 0.0f;
    for (int k = 0; k < NLB; k++)
        s += counts[((size_t)(b * NLB + k)) * PQ + r];
    cdf[idx] = s * (1.0f / (float)Ll);
}

// ---------------------------------------------------------------------------
extern "C" void kernel_launch(void* const* d_in, const int* in_sizes, int n_in,
                              void* d_out, int out_size, void* d_ws, size_t ws_size,
                              hipStream_t stream) {
    const float* X    = (const float*)d_in[0];   // [B,C,L]
    const float* proj = (const float*)d_in[1];   // [P,C]
    const float* mn   = (const float*)d_in[2];   // [P]
    const float* mx   = (const float*)d_in[3];   // [P]

    float* cdf     = (float*)d_out;              // [B, P*Q]
    float* set_out = cdf + (size_t)Bsz * PQ;     // [B, P*Q, L]

    const size_t counts_bytes = (size_t)Bsz * NLB * PQ * sizeof(float); // 8.192 MB

    int use_atomic;
    float* counts = nullptr;
    if (ws_size >= counts_bytes) {
        use_atomic = 0;
        counts = (float*)d_ws;
    } else {
        use_atomic = 1;  // fallback: atomics straight into cdf
    }

    if (use_atomic) hipMemsetAsync(cdf, 0, (size_t)Bsz * PQ * sizeof(float), stream);

    dim3 grid(NLB, Bsz);
    csf_main<<<grid, 256, 0, stream>>>(X, proj, mn, mx, cdf, set_out, counts, use_atomic);

    if (!use_atomic)
        csf_reduce<<<(Bsz * PQ + 255) / 256, 256, 0, stream>>>(counts, cdf);
}

// Round 4
// 603.051 us; speedup vs baseline: 1.1236x; 1.1236x over previous
//
#include <hip/hip_runtime.h>

// Problem constants (from reference)
#define Bsz 16
#define Cc  256
#define Ll  4096
#define Pp  100
#define Qq  20
#define PQ  (Pp * Qq)     // 2000

// Tiling: block = 256 threads = 4 waves; lane owns 4 consecutive l (float4).
// Block covers LTILE=1024 l's and GP=10 p's -> per (p,q) row the block writes
// 4 KB CONTIGUOUS (4 waves x 1 KB adjacent) -> full HBM row-activation writes.
#define LTILE 1024
#define NLT   (Ll / LTILE)   // 4
#define GP    10
#define NPG   (Pp / GP)      // 10

// native vector type for nontemporal builtin (HIP_vector_type is rejected)
typedef float f32x4 __attribute__((ext_vector_type(4)));

// ---------------------------------------------------------------------------
// NUMERICS CONTRACT (bit-exact vs numpy fp32 reference, validated R2):
//   a[b,p,l]: chain c=0..255 of a = fmaf(X[b,c,l], proj[p,c], a)      [fp32]
//   thr[p,q] = fadd(mn, fmul(fsub(mx,mn), fdiv(q+1, 21)))             [fp32,
//              separate roundings, no contraction]
//   cdf = popcount/4096 (exact dyadic fp32; atomic order irrelevant)
// ---------------------------------------------------------------------------
__global__ __launch_bounds__(256) void csf_main(
    const float* __restrict__ X,
    const float* __restrict__ proj,
    const float* __restrict__ mn,
    const float* __restrict__ mx,
    float* __restrict__ cdf,       // d_out[0 .. B*P*Q), zeroed before launch
    float* __restrict__ set_out) { // d_out + B*P*Q, [B][P*Q][L]
    const int lt  = blockIdx.x;                 // 0..NLT-1
    const int pg  = blockIdx.y;                 // 0..NPG-1
    const int b   = blockIdx.z;                 // 0..Bsz-1
    const int tid = threadIdx.x;
    const int l0  = lt * LTILE + tid * 4;       // 4 consecutive l per lane
    const int p0  = __builtin_amdgcn_readfirstlane(pg * GP);  // wave-uniform

    const float* Xb = X + (size_t)b * Cc * Ll + l0;  // c-th element block at +c*Ll

    float acc[GP][4];
#pragma unroll
    for (int i = 0; i < GP; i++)
#pragma unroll
        for (int k = 0; k < 4; k++) acc[i][k] = 0.0f;

    // fp32 FMA chains, c strictly ascending per accumulator (numpy order).
    // proj index is wave-uniform -> scalar loads; x is a 16B coalesced load.
#pragma unroll 4
    for (int c = 0; c < Cc; c++) {
        const f32x4 x = *(const f32x4*)(Xb + (size_t)c * Ll);
#pragma unroll
        for (int i = 0; i < GP; i++) {
            const float w = proj[(size_t)(p0 + i) * Cc + c];
            acc[i][0] = __builtin_fmaf(x.x, w, acc[i][0]);
            acc[i][1] = __builtin_fmaf(x.y, w, acc[i][1]);
            acc[i][2] = __builtin_fmaf(x.z, w, acc[i][2]);
            acc[i][3] = __builtin_fmaf(x.w, w, acc[i][3]);
        }
    }

    // fracs: fl((q+1)/21), IEEE division — same as np.arange/np.float32(21)
    float fr[Qq];
#pragma unroll
    for (int q = 0; q < Qq; q++) fr[q] = __fdiv_rn((float)(q + 1), 21.0f);

    float* ob = set_out + (size_t)b * PQ * Ll + l0;   // + (p*Q+q)*Ll
    const bool lane0 = ((tid & 63) == 0);

#pragma unroll 1
    for (int i = 0; i < GP; i++) {
        const int p = p0 + i;
        const float mnp = mn[p];
        const float mxp = mx[p];
        const float d = __fsub_rn(mxp, mnp);          // fl(mx-mn)
#pragma unroll
        for (int q = 0; q < Qq; q++) {
            // fl(mn + fl(d*frac)) — separate roundings, no FMA contraction
            const float thr = __fadd_rn(mnp, __fmul_rn(d, fr[q]));
            const bool b0 = acc[i][0] < thr;
            const bool b1 = acc[i][1] < thr;
            const bool b2 = acc[i][2] < thr;
            const bool b3 = acc[i][3] < thr;
            f32x4 o;
            o.x = b0 ? 1.0f : 0.0f;
            o.y = b1 ? 1.0f : 0.0f;
            o.z = b2 ? 1.0f : 0.0f;
            o.w = b3 ? 1.0f : 0.0f;
            // streaming, never re-read -> non-temporal (keep L2 for X)
            __builtin_nontemporal_store(o, (f32x4*)(ob + (size_t)(p * Qq + q) * Ll));
            // per-wave count: 4 ballots (one per sub-l bit)
            const int cnt = __popcll(__ballot(b0)) + __popcll(__ballot(b1))
                          + __popcll(__ballot(b2)) + __popcll(__ballot(b3));
            if (lane0) {
                // exact: every term is a multiple of 2^-12, sums are dyadic <=1
                atomicAdd(&cdf[(size_t)b * PQ + p * Qq + q],
                          (float)cnt * (1.0f / (float)Ll));
            }
        }
    }
}

// ---------------------------------------------------------------------------
extern "C" void kernel_launch(void* const* d_in, const int* in_sizes, int n_in,
                              void* d_out, int out_size, void* d_ws, size_t ws_size,
                              hipStream_t stream) {
    const float* X    = (const float*)d_in[0];   // [B,C,L]
    const float* proj = (const float*)d_in[1];   // [P,C]
    const float* mn   = (const float*)d_in[2];   // [P]
    const float* mx   = (const float*)d_in[3];   // [P]

    float* cdf     = (float*)d_out;              // [B, P*Q]
    float* set_out = cdf + (size_t)Bsz * PQ;     // [B, P*Q, L]

    // zero cdf for atomic accumulation (128 KB, ~2 us)
    (void)hipMemsetAsync(cdf, 0, (size_t)Bsz * PQ * sizeof(float), stream);

    dim3 grid(NLT, NPG, Bsz);
    csf_main<<<grid, 256, 0, stream>>>(X, proj, mn, mx, cdf, set_out);
}